// Round 7
// baseline (198.436 us; speedup 1.0000x reference)
//
#include <hip/hip_runtime.h>
#include <cmath>

// MemoryEfficientAttention: x[2,2048,1024] -> qkv -> 16-head attn -> proj.
// Round 6: attention v3 — wave=64 q-rows (4 qt tiles), block=128 thr,
// grid 512 (2 blocks/CU); exp2 with scale+log2e folded into Q; truncating
// P->bf16; row-sums via ones-MFMA. GEMMs unchanged from round 5.

namespace {
constexpr int kDim   = 1024;
constexpr int kHeads = 16;
constexpr int kHd    = 64;
constexpr int kB     = 2;
constexpr int kN     = 2048;
constexpr int kM     = kB * kN;
constexpr float kScale  = 0.125f;                       // 1/sqrt(64)
constexpr float kQScale = 0.125f * 1.44269504088896f;   // fold log2(e)
constexpr int kP = 72;              // padded LDS stride (attn P / path C)
}  // namespace

typedef __attribute__((ext_vector_type(8))) short bf16x8;
typedef __attribute__((ext_vector_type(4))) float f32x4;

#if __has_builtin(__builtin_amdgcn_exp2f)
#define EXP2(x) __builtin_amdgcn_exp2f(x)
#else
#define EXP2(x) __expf((x) * 0.6931471805599453f)
#endif

__device__ inline unsigned short f2bf(float x) {
  union { float f; unsigned u; } un; un.f = x;
  unsigned r = un.u + 0x7fffu + ((un.u >> 16) & 1u);   // RNE
  return (unsigned short)(r >> 16);
}
__device__ inline short tbf(float x) {                 // truncate (fast)
  union { float f; unsigned u; } un; un.f = x;
  return (short)(un.u >> 16);
}
__device__ inline unsigned pack2bf(float x, float y) {
  return (unsigned)f2bf(x) | ((unsigned)f2bf(y) << 16);
}
__device__ inline void gl_lds16(const short* g, short* l) {
  __builtin_amdgcn_global_load_lds(
      (const __attribute__((address_space(1))) unsigned*)g,
      (__attribute__((address_space(3))) unsigned*)l, 16, 0, 0);
}

// ---------------------------------------------------------------------------
// Merged fp32->bf16 convert: blocks [0,n0) -> a, [n0,n0+n1) -> b, rest -> c.
__global__ __launch_bounds__(256) void cvt3_kernel(
    const float* __restrict__ a, short* __restrict__ da, int n0,
    const float* __restrict__ b, short* __restrict__ db, int n1,
    const float* __restrict__ c, short* __restrict__ dc) {
  int blk = blockIdx.x;
  const float* src; short* dst;
  if (blk < n0) { src = a; dst = da; }
  else if (blk < n0 + n1) { src = b; dst = db; blk -= n0; }
  else { src = c; dst = dc; blk -= n0 + n1; }
  const int i = (blk * 256 + threadIdx.x) * 8;
  float4 u = *(const float4*)&src[i];
  float4 v = *(const float4*)&src[i + 4];
  bf16x8 o = {(short)f2bf(u.x), (short)f2bf(u.y), (short)f2bf(u.z), (short)f2bf(u.w),
              (short)f2bf(v.x), (short)f2bf(v.y), (short)f2bf(v.z), (short)f2bf(v.w)};
  *(bf16x8*)&dst[i] = o;
}

// ---------------------------------------------------------------------------
// QKV GEMM (path A): A16[4096,1024] @ W16[3072,1024]^T. 128x128 tile, BK=64,
// global_load_lds + XOR swizzle. Epilogue: Q scaled by kQScale -> [b][h][n][dh];
// K -> [b][h][n][dh]; V -> TRANSPOSED [b][h][dh][n] via per-wave LDS bounce.
__global__ __launch_bounds__(256, 2) void mm_qkv_kernel(
    const short* __restrict__ A16, const short* __restrict__ W16,
    short* __restrict__ q16, short* __restrict__ k16, short* __restrict__ vT16) {
  __shared__ short smem[2 * 128 * 64];
  short* As = smem;
  short* Bs = smem + 128 * 64;
  const int tid  = threadIdx.x;
  const int w    = tid >> 6;
  const int lane = tid & 63;
  const int quad = lane >> 4;
  const int k15  = lane & 15;
  const int m0   = blockIdx.x * 128;
  const int seg  = blockIdx.y >> 3;
  const int nt0  = (blockIdx.y & 7) << 7;
  const int wrow0 = seg * 1024 + nt0;
  const int wm = (w >> 1) * 64;
  const int wn = (w & 1) * 64;
  const int lrow   = lane >> 3;
  const int lchunk = (lane & 7) ^ lrow;

  f32x4 acc[4][4];
#pragma unroll
  for (int i = 0; i < 4; ++i)
#pragma unroll
    for (int j = 0; j < 4; ++j) acc[i][j] = (f32x4){0.f, 0.f, 0.f, 0.f};

  for (int kt = 0; kt < 1024; kt += 64) {
    __syncthreads();
#pragma unroll
    for (int p = 0; p < 4; ++p) {
      const int r0 = p * 32 + w * 8;
      gl_lds16(&A16[(long)(m0 + r0 + lrow) * 1024 + kt + lchunk * 8], &As[r0 * 64]);
      gl_lds16(&W16[(long)(wrow0 + r0 + lrow) * 1024 + kt + lchunk * 8], &Bs[r0 * 64]);
    }
    __syncthreads();
#pragma unroll
    for (int ks = 0; ks < 2; ++ks) {
      bf16x8 af[4], bf[4];
#pragma unroll
      for (int t = 0; t < 4; ++t) {
        const int Ra = wm + t * 16 + k15;
        af[t] = *(const bf16x8*)&As[Ra * 64 + (((ks << 2) + quad) ^ (Ra & 7)) * 8];
        const int Rb = wn + t * 16 + k15;
        bf[t] = *(const bf16x8*)&Bs[Rb * 64 + (((ks << 2) + quad) ^ (Rb & 7)) * 8];
      }
#pragma unroll
      for (int mt = 0; mt < 4; ++mt)
#pragma unroll
        for (int nt = 0; nt < 4; ++nt)
          acc[mt][nt] = __builtin_amdgcn_mfma_f32_16x16x32_bf16(
              af[mt], bf[nt], acc[mt][nt], 0, 0, 0);
    }
  }

  if (seg < 2) {
    short* dst = (seg == 0) ? q16 : k16;
    const float sc = (seg == 0) ? kQScale : 1.0f;
#pragma unroll
    for (int nt = 0; nt < 4; ++nt) {
      const int dl = nt0 + wn + nt * 16 + k15;
      const int h  = dl >> 6;
      const int dh = dl & 63;
#pragma unroll
      for (int mt = 0; mt < 4; ++mt) {
#pragma unroll
        for (int r = 0; r < 4; ++r) {
          const int ml = m0 + wm + mt * 16 + quad * 4 + r;
          const int b  = ml >> 11;
          const int n  = ml & 2047;
          dst[(((long)(b * kHeads + h) * kN) + n) * kHd + dh] =
              (short)f2bf(acc[mt][nt][r] * sc);
        }
      }
    }
  } else {
    __syncthreads();
    short* Tw = smem + w * 16 * kP;
#pragma unroll
    for (int nt = 0; nt < 4; ++nt) {
#pragma unroll
      for (int mt = 0; mt < 4; ++mt) {
        uint2 pk;
        pk.x = pack2bf(acc[mt][nt][0], acc[mt][nt][1]);
        pk.y = pack2bf(acc[mt][nt][2], acc[mt][nt][3]);
        *(uint2*)&Tw[k15 * kP + mt * 16 + quad * 4] = pk;
      }
#pragma unroll
      for (int i = 0; i < 2; ++i) {
        const int idx  = i * 64 + lane;
        const int trow = idx >> 3;
        const int tch  = idx & 7;
        bf16x8 row = *(const bf16x8*)&Tw[trow * kP + tch * 8];
        const int vcol = nt0 + wn + nt * 16 + trow;
        const int h  = vcol >> 6;
        const int dh = vcol & 63;
        const int m  = m0 + wm + tch * 8;
        const int b  = m >> 11;
        const int n  = m & 2047;
        *(bf16x8*)&vT16[(((long)(b * kHeads + h) * kHd) + dh) * kN + n] = row;
      }
    }
  }
}

// ---------------------------------------------------------------------------
// proj GEMM: out = ao16[4096,1024] @ PW16[1024,1024]^T + bias (fp32 out).
__global__ __launch_bounds__(256, 2) void mm_proj_kernel(
    const short* __restrict__ A16, const short* __restrict__ B16,
    const float* __restrict__ bias, float* __restrict__ out) {
  __shared__ short As[128 * 64];
  __shared__ short Bs[128 * 64];
  const int tid  = threadIdx.x;
  const int w    = tid >> 6;
  const int lane = tid & 63;
  const int quad = lane >> 4;
  const int k15  = lane & 15;
  const int m0 = blockIdx.x * 128;
  const int n0 = blockIdx.y * 128;
  const int wm = (w >> 1) * 64;
  const int wn = (w & 1) * 64;
  const int lrow   = lane >> 3;
  const int lchunk = (lane & 7) ^ lrow;

  f32x4 acc[4][4];
#pragma unroll
  for (int i = 0; i < 4; ++i)
#pragma unroll
    for (int j = 0; j < 4; ++j) acc[i][j] = (f32x4){0.f, 0.f, 0.f, 0.f};

  for (int kt = 0; kt < 1024; kt += 64) {
    __syncthreads();
#pragma unroll
    for (int p = 0; p < 4; ++p) {
      const int r0 = p * 32 + w * 8;
      gl_lds16(&A16[(long)(m0 + r0 + lrow) * 1024 + kt + lchunk * 8], &As[r0 * 64]);
      gl_lds16(&B16[(long)(n0 + r0 + lrow) * 1024 + kt + lchunk * 8], &Bs[r0 * 64]);
    }
    __syncthreads();
#pragma unroll
    for (int ks = 0; ks < 2; ++ks) {
      bf16x8 af[4], bf[4];
#pragma unroll
      for (int t = 0; t < 4; ++t) {
        const int Ra = wm + t * 16 + k15;
        af[t] = *(const bf16x8*)&As[Ra * 64 + (((ks << 2) + quad) ^ (Ra & 7)) * 8];
        const int Rb = wn + t * 16 + k15;
        bf[t] = *(const bf16x8*)&Bs[Rb * 64 + (((ks << 2) + quad) ^ (Rb & 7)) * 8];
      }
#pragma unroll
      for (int mt = 0; mt < 4; ++mt)
#pragma unroll
        for (int nt = 0; nt < 4; ++nt)
          acc[mt][nt] = __builtin_amdgcn_mfma_f32_16x16x32_bf16(
              af[mt], bf[nt], acc[mt][nt], 0, 0, 0);
    }
  }

#pragma unroll
  for (int nt = 0; nt < 4; ++nt) {
    const int d = n0 + wn + nt * 16 + k15;
    const float bb = bias[d];
#pragma unroll
    for (int mt = 0; mt < 4; ++mt) {
#pragma unroll
      for (int r = 0; r < 4; ++r) {
        const int m = m0 + wm + mt * 16 + quad * 4 + r;
        out[(long)m * 1024 + d] = acc[mt][nt][r] + bb;
      }
    }
  }
}

// ---------------------------------------------------------------------------
// Flash attention v3: wave = 64 q-rows (4x16), block = 2 waves = 128 q-rows.
// 128-key tiles; K [h][n][dh], V^T [h][dh][n] via global_load_lds + swizzle.
// Q pre-scaled by 0.125*log2(e) -> P = exp2(S). Row sums via ones-MFMA.
__global__ __launch_bounds__(128, 2) void attn_kernel(
    const short* __restrict__ q16, const short* __restrict__ k16,
    const short* __restrict__ vT16, short* __restrict__ ao16) {
  __shared__ short Ks[128 * 64];        // [key][dh] chunk-swizzled
  __shared__ short Vs[64 * 128];        // [dh][key] chunk-swizzled
  __shared__ short Ps[2 * 2 * 16 * kP]; // [wave][parity][16 q][64 key]

  const int tid  = threadIdx.x;         // 0..127
  const int w    = tid >> 6;            // 0..1
  const int lane = tid & 63;
  const int quad = lane >> 4;
  const int k15  = lane & 15;
  const int lrow  = lane >> 3;          // K staging
  const int lch8  = lane & 7;
  const int lrow4 = lane >> 4;          // V staging
  const int lch16 = lane & 15;
  const int bufIdx = blockIdx.z * kHeads + blockIdx.y;
  const long base  = (long)bufIdx * kN * kHd;

  // Q A-frags: 4 qt tiles x 2 k-steps
  bf16x8 qf[4][2];
#pragma unroll
  for (int qt = 0; qt < 4; ++qt) {
    const long qr = base + (long)(blockIdx.x * 128 + w * 64 + qt * 16 + k15) * kHd;
#pragma unroll
    for (int ks = 0; ks < 2; ++ks)
      qf[qt][ks] = *(const bf16x8*)&q16[qr + ks * 32 + quad * 8];
  }

  // ones B-frag: column n=0 all ones (for row sums via MFMA)
  const short oneb = (short)0x3F80;
  bf16x8 onesf;
#pragma unroll
  for (int j = 0; j < 8; ++j) onesf[j] = (k15 == 0) ? oneb : (short)0;

  f32x4 accO[4][4];
#pragma unroll
  for (int qt = 0; qt < 4; ++qt)
#pragma unroll
    for (int d = 0; d < 4; ++d) accO[qt][d] = (f32x4){0.f, 0.f, 0.f, 0.f};
  f32x4 accL[4] = {{0.f,0.f,0.f,0.f},{0.f,0.f,0.f,0.f},
                   {0.f,0.f,0.f,0.f},{0.f,0.f,0.f,0.f}};

  for (int kt = 0; kt < kN / 128; ++kt) {
    __syncthreads();
    {
      const short* kg = k16 + base + (long)kt * 128 * kHd;
      const short* vg = vT16 + base + kt * 128;
#pragma unroll
      for (int c = 0; c < 8; ++c) {
        const int r0 = w * 64 + c * 8;
        gl_lds16(kg + (long)(r0 + lrow) * kHd + (lch8 ^ ((r0 + lrow) & 7)) * 8,
                 &Ks[r0 * 64]);
      }
#pragma unroll
      for (int c = 0; c < 8; ++c) {
        const int r0v = w * 32 + c * 4;
        gl_lds16(vg + (long)(r0v + lrow4) * kN + (lch16 ^ ((r0v + lrow4) & 15)) * 8,
                 &Vs[r0v * 128]);
      }
    }
    __syncthreads();

#pragma unroll
    for (int h2 = 0; h2 < 2; ++h2) {
      // K B-frags (shared across qt)
      bf16x8 kb[4][2];
#pragma unroll
      for (int t = 0; t < 4; ++t) {
        const int row = h2 * 64 + t * 16 + k15;
#pragma unroll
        for (int ks = 0; ks < 2; ++ks)
          kb[t][ks] = *(const bf16x8*)&Ks[row * 64 + (((ks << 2) + quad) ^ (row & 7)) * 8];
      }
      // V B-frags (shared across qt)
      bf16x8 vb[2][4];
#pragma unroll
      for (int kc = 0; kc < 2; ++kc)
#pragma unroll
        for (int d = 0; d < 4; ++d) {
          const int vrow = d * 16 + k15;
          const int ch = (h2 * 8 + kc * 4 + quad) ^ (vrow & 15);
          vb[kc][d] = *(const bf16x8*)&Vs[vrow * 128 + ch * 8];
        }

#pragma unroll
      for (int qt = 0; qt < 4; ++qt) {
        f32x4 sc[4];
#pragma unroll
        for (int t = 0; t < 4; ++t) {
          f32x4 z = {0.f, 0.f, 0.f, 0.f};
          z = __builtin_amdgcn_mfma_f32_16x16x32_bf16(qf[qt][0], kb[t][0], z, 0, 0, 0);
          z = __builtin_amdgcn_mfma_f32_16x16x32_bf16(qf[qt][1], kb[t][1], z, 0, 0, 0);
          sc[t] = z;
        }
        short* pw = Ps + (w * 2 + (qt & 1)) * 16 * kP;
#pragma unroll
        for (int t = 0; t < 4; ++t)
#pragma unroll
          for (int r = 0; r < 4; ++r)
            pw[(quad * 4 + r) * kP + t * 16 + k15] = tbf(EXP2(sc[t][r]));
#pragma unroll
        for (int kc = 0; kc < 2; ++kc) {
          bf16x8 pf = *(const bf16x8*)&pw[k15 * kP + kc * 32 + quad * 8];
#pragma unroll
          for (int d = 0; d < 4; ++d)
            accO[qt][d] = __builtin_amdgcn_mfma_f32_16x16x32_bf16(
                pf, vb[kc][d], accO[qt][d], 0, 0, 0);
          accL[qt] = __builtin_amdgcn_mfma_f32_16x16x32_bf16(
              pf, onesf, accL[qt], 0, 0, 0);
        }
      }
    }
  }

#pragma unroll
  for (int qt = 0; qt < 4; ++qt) {
#pragma unroll
    for (int r = 0; r < 4; ++r) {
      const float s  = __shfl(accL[qt][r], (lane & 48));  // lane quad*16, col 0
      const float in = 1.f / s;
      const int gq = blockIdx.x * 128 + w * 64 + qt * 16 + quad * 4 + r;
      short* drow = ao16 + ((long)(blockIdx.z * kN + gq)) * kDim + blockIdx.y * kHd;
#pragma unroll
      for (int d = 0; d < 4; ++d)
        drow[d * 16 + k15] = (short)f2bf(accO[qt][d][r] * in);
    }
  }
}

// ---------------------------------------------------------------------------
// Path C fallback (proven r3-style, 20 MiB): fp32-input VGPR-staged kernels.
__global__ __launch_bounds__(256, 2) void r3_qkv_kernel(
    const float* __restrict__ X, const float* __restrict__ W,
    short* __restrict__ q16, short* __restrict__ k16, short* __restrict__ v16) {
  __shared__ short As[128 * kP];
  __shared__ short Ws[128 * kP];
  const int tid  = threadIdx.x;
  const int w    = tid >> 6;
  const int lane = tid & 63;
  const int quad = lane >> 4;
  const int k15  = lane & 15;
  const int m0 = blockIdx.x * 128;
  const int n0 = blockIdx.y * 128;
  const int wm = (w >> 1) * 64;
  const int wn = (w & 1) * 64;

  f32x4 acc[4][4];
#pragma unroll
  for (int i = 0; i < 4; ++i)
#pragma unroll
    for (int j = 0; j < 4; ++j) acc[i][j] = (f32x4){0.f, 0.f, 0.f, 0.f};

  for (int kt = 0; kt < kDim; kt += 64) {
    __syncthreads();
#pragma unroll
    for (int p = 0; p < 8; ++p) {
      const int idx = p * 256 + tid;
      const int row = idx >> 4;
      const int c4  = (idx & 15) << 2;
      float4 av = *(const float4*)&X[(long)(m0 + row) * kDim + kt + c4];
      uint2 ap = {pack2bf(av.x, av.y), pack2bf(av.z, av.w)};
      *(uint2*)&As[row * kP + c4] = ap;
      float4 wv = *(const float4*)&W[(long)(n0 + row) * kDim + kt + c4];
      uint2 wp = {pack2bf(wv.x, wv.y), pack2bf(wv.z, wv.w)};
      *(uint2*)&Ws[row * kP + c4] = wp;
    }
    __syncthreads();
#pragma unroll
    for (int ks = 0; ks < 2; ++ks) {
      bf16x8 af[4], bf[4];
#pragma unroll
      for (int t = 0; t < 4; ++t) {
        af[t] = *(const bf16x8*)&As[(wm + t * 16 + k15) * kP + ks * 32 + quad * 8];
        bf[t] = *(const bf16x8*)&Ws[(wn + t * 16 + k15) * kP + ks * 32 + quad * 8];
      }
#pragma unroll
      for (int mt = 0; mt < 4; ++mt)
#pragma unroll
        for (int nt = 0; nt < 4; ++nt)
          acc[mt][nt] = __builtin_amdgcn_mfma_f32_16x16x32_bf16(
              af[mt], bf[nt], acc[mt][nt], 0, 0, 0);
    }
  }

  const int t_sel = n0 >> 10;
  short* dst = (t_sel == 0) ? q16 : (t_sel == 1) ? k16 : v16;
  const float scl = (t_sel == 0) ? kScale : 1.0f;
#pragma unroll
  for (int nt = 0; nt < 4; ++nt) {
    const int d  = n0 + wn + nt * 16 + k15;
    const int h  = (d >> 6) & 15;
    const int dh = d & 63;
#pragma unroll
    for (int mt = 0; mt < 4; ++mt) {
#pragma unroll
      for (int r = 0; r < 4; ++r) {
        const int m = m0 + wm + mt * 16 + quad * 4 + r;
        dst[((long)h * kN + m) * kHd + dh] = (short)f2bf(acc[mt][nt][r] * scl);
      }
    }
  }
}

__global__ __launch_bounds__(256, 4) void attn_v1_kernel(
    const short* __restrict__ q16, const short* __restrict__ k16,
    const short* __restrict__ v16, short* __restrict__ ao16, int bpar) {
  __shared__ short Ks[64 * kP];
  __shared__ short Vs[64 * kP];
  __shared__ short Ps[4 * 16 * kP];
  const int tid  = threadIdx.x;
  const int w    = tid >> 6;
  const int lane = tid & 63;
  const int quad = lane >> 4;
  const int k15  = lane & 15;
  const long base = (long)blockIdx.y * kN * kHd;
  const int qrow = blockIdx.x * 64 + w * 16 + k15;
  const short* qp = q16 + base + (long)qrow * kHd + quad * 8;
  bf16x8 qf0 = *(const bf16x8*)(qp);
  bf16x8 qf1 = *(const bf16x8*)(qp + 32);

  f32x4 accO[4] = {{0.f,0.f,0.f,0.f},{0.f,0.f,0.f,0.f},
                   {0.f,0.f,0.f,0.f},{0.f,0.f,0.f,0.f}};
  float lsum[4] = {0.f, 0.f, 0.f, 0.f};

  for (int kt = 0; kt < kN / 64; ++kt) {
    __syncthreads();
    {
      const short* kg = k16 + base + (long)kt * 64 * kHd;
      const short* vg = v16 + base + (long)kt * 64 * kHd;
#pragma unroll
      for (int p = 0; p < 2; ++p) {
        const int idx = p * 256 + tid;
        const int key = idx >> 3;
        const int c8  = (idx & 7) << 3;
        *(bf16x8*)&Ks[key * kP + c8] = *(const bf16x8*)&kg[key * kHd + c8];
        bf16x8 vv = *(const bf16x8*)&vg[key * kHd + c8];
#pragma unroll
        for (int j = 0; j < 8; ++j) Vs[(c8 + j) * kP + key] = vv[j];
      }
    }
    __syncthreads();

    f32x4 sc[4];
#pragma unroll
    for (int t = 0; t < 4; ++t) {
      bf16x8 kb0 = *(const bf16x8*)&Ks[(t * 16 + k15) * kP + quad * 8];
      bf16x8 kb1 = *(const bf16x8*)&Ks[(t * 16 + k15) * kP + 32 + quad * 8];
      f32x4 z = {0.f, 0.f, 0.f, 0.f};
      z = __builtin_amdgcn_mfma_f32_16x16x32_bf16(qf0, kb0, z, 0, 0, 0);
      z = __builtin_amdgcn_mfma_f32_16x16x32_bf16(qf1, kb1, z, 0, 0, 0);
      sc[t] = z;
    }
    short* pw = &Ps[w * (16 * kP)];
#pragma unroll
    for (int t = 0; t < 4; ++t) {
#pragma unroll
      for (int r = 0; r < 4; ++r) {
        const float p = __expf(sc[t][r]);
        lsum[r] += p;
        pw[(quad * 4 + r) * kP + t * 16 + k15] = (short)f2bf(p);
      }
    }
    bf16x8 pf0 = *(const bf16x8*)&pw[k15 * kP + quad * 8];
    bf16x8 pf1 = *(const bf16x8*)&pw[k15 * kP + 32 + quad * 8];
#pragma unroll
    for (int t = 0; t < 4; ++t) {
      bf16x8 vb0 = *(const bf16x8*)&Vs[(t * 16 + k15) * kP + quad * 8];
      bf16x8 vb1 = *(const bf16x8*)&Vs[(t * 16 + k15) * kP + 32 + quad * 8];
      accO[t] = __builtin_amdgcn_mfma_f32_16x16x32_bf16(pf0, vb0, accO[t], 0, 0, 0);
      accO[t] = __builtin_amdgcn_mfma_f32_16x16x32_bf16(pf1, vb1, accO[t], 0, 0, 0);
    }
  }

#pragma unroll
  for (int r = 0; r < 4; ++r) {
    float s = lsum[r];
    s += __shfl_xor(s, 1);
    s += __shfl_xor(s, 2);
    s += __shfl_xor(s, 4);
    s += __shfl_xor(s, 8);
    lsum[r] = 1.f / s;
  }
#pragma unroll
  for (int r = 0; r < 4; ++r) {
    const int gq = blockIdx.x * 64 + w * 16 + quad * 4 + r;
    short* drow = ao16 + ((long)(bpar * kN + gq)) * kDim + blockIdx.y * kHd;
#pragma unroll
    for (int t = 0; t < 4; ++t)
      drow[t * 16 + k15] = (short)f2bf(accO[t][r] * lsum[r]);
  }
}

__global__ __launch_bounds__(256, 2) void r3_proj_kernel(
    const short* __restrict__ A16, const float* __restrict__ W,
    const float* __restrict__ bias, float* __restrict__ out) {
  __shared__ short As[128 * kP];
  __shared__ short Ws[128 * kP];
  const int tid  = threadIdx.x;
  const int w    = tid >> 6;
  const int lane = tid & 63;
  const int quad = lane >> 4;
  const int k15  = lane & 15;
  const int m0 = blockIdx.x * 128;
  const int n0 = blockIdx.y * 128;
  const int wm = (w >> 1) * 64;
  const int wn = (w & 1) * 64;

  f32x4 acc[4][4];
#pragma unroll
  for (int i = 0; i < 4; ++i)
#pragma unroll
    for (int j = 0; j < 4; ++j) acc[i][j] = (f32x4){0.f, 0.f, 0.f, 0.f};

  for (int kt = 0; kt < kDim; kt += 64) {
    __syncthreads();
#pragma unroll
    for (int p = 0; p < 4; ++p) {
      const int idx = p * 256 + tid;
      const int row = idx >> 3;
      const int c8  = (idx & 7) << 3;
      *(bf16x8*)&As[row * kP + c8] =
          *(const bf16x8*)&A16[(long)(m0 + row) * kDim + kt + c8];
    }
#pragma unroll
    for (int p = 0; p < 8; ++p) {
      const int idx = p * 256 + tid;
      const int row = idx >> 4;
      const int c4  = (idx & 15) << 2;
      float4 wv = *(const float4*)&W[(long)(n0 + row) * kDim + kt + c4];
      uint2 wp = {pack2bf(wv.x, wv.y), pack2bf(wv.z, wv.w)};
      *(uint2*)&Ws[row * kP + c4] = wp;
    }
    __syncthreads();
#pragma unroll
    for (int ks = 0; ks < 2; ++ks) {
      bf16x8 af[4], bf[4];
#pragma unroll
      for (int t = 0; t < 4; ++t) {
        af[t] = *(const bf16x8*)&As[(wm + t * 16 + k15) * kP + ks * 32 + quad * 8];
        bf[t] = *(const bf16x8*)&Ws[(wn + t * 16 + k15) * kP + ks * 32 + quad * 8];
      }
#pragma unroll
      for (int mt = 0; mt < 4; ++mt)
#pragma unroll
        for (int nt = 0; nt < 4; ++nt)
          acc[mt][nt] = __builtin_amdgcn_mfma_f32_16x16x32_bf16(
              af[mt], bf[nt], acc[mt][nt], 0, 0, 0);
    }
  }

#pragma unroll
  for (int nt = 0; nt < 4; ++nt) {
    const int d = n0 + wn + nt * 16 + k15;
    const float bb = bias[d];
#pragma unroll
    for (int mt = 0; mt < 4; ++mt) {
#pragma unroll
      for (int r = 0; r < 4; ++r) {
        const int m = m0 + wm + mt * 16 + quad * 4 + r;
        out[(long)m * kDim + d] = acc[mt][nt][r] + bb;
      }
    }
  }
}

// ---------------------------------------------------------------------------
extern "C" void kernel_launch(void* const* d_in, const int* in_sizes, int n_in,
                              void* d_out, int out_size, void* d_ws, size_t ws_size,
                              hipStream_t stream) {
  const float* x      = (const float*)d_in[0];
  const float* qkv_w  = (const float*)d_in[1];
  const float* proj_w = (const float*)d_in[2];
  const float* proj_b = (const float*)d_in[3];
  float* out = (float*)d_out;

  short* ws = (short*)d_ws;
  const size_t MiS = 1048576;

  if (ws_size >= 41943040ull) {
    // Path A (40 MiB): X16 aliased with ao.
    short* X16  = ws;              // [4096,1024]
    short* W16  = ws + 4 * MiS;    // [3072,1024]
    short* PW16 = ws + 7 * MiS;    // [1024,1024]
    short* q16  = ws + 8 * MiS;    // [2][16][2048][64]
    short* k16  = ws + 12 * MiS;   // [2][16][2048][64]
    short* vT16 = ws + 16 * MiS;   // [2][16][64][2048]
    short* ao16 = X16;

    cvt3_kernel<<<4096, 256, 0, stream>>>(x, X16, 2048, qkv_w, W16, 1536,
                                          proj_w, PW16);
    mm_qkv_kernel<<<dim3(32, 24), 256, 0, stream>>>(X16, W16, q16, k16, vT16);
    attn_kernel<<<dim3(16, 16, 2), 128, 0, stream>>>(q16, k16, vT16, ao16);
    mm_proj_kernel<<<dim3(32, 8), 256, 0, stream>>>(ao16, PW16, proj_b, out);
    return;
  }

  // Path C fallback (20 MiB, proven structure).
  {
    short* q16  = ws;
    short* k16  = ws + 2 * MiS;
    short* v16  = ws + 4 * MiS;
    short* ao16 = ws + 6 * MiS;
    for (int b = 0; b < kB; ++b) {
      r3_qkv_kernel<<<dim3(16, 24), 256, 0, stream>>>(
          x + (size_t)b * kN * kDim, qkv_w, q16, k16, v16);
      attn_v1_kernel<<<dim3(32, 16), 256, 0, stream>>>(q16, k16, v16, ao16, b);
    }
    r3_proj_kernel<<<dim3(32, 8), 256, 0, stream>>>(ao16, proj_w, proj_b, out);
  }
}

// Round 8
// 177.931 us; speedup vs baseline: 1.1152x; 1.1152x over previous
//
#include <hip/hip_runtime.h>
#include <cmath>

// MemoryEfficientAttention: x[2,2048,1024] -> qkv -> 16-head attn -> proj.
// Round 7: attention v4 = r5 occupancy shape (wave=32 q-rows, 4-wave blocks,
// grid 512, 2 waves/SIMD) + r6 VALU cuts (exp2 w/ folded scale, truncating
// P->bf16, ones-MFMA row sums). GEMMs unchanged.

namespace {
constexpr int kDim   = 1024;
constexpr int kHeads = 16;
constexpr int kHd    = 64;
constexpr int kB     = 2;
constexpr int kN     = 2048;
constexpr int kM     = kB * kN;
constexpr float kScale  = 0.125f;                       // 1/sqrt(64)
constexpr float kQScale = 0.125f * 1.44269504088896f;   // fold log2(e)
constexpr int kP = 72;              // padded LDS stride (attn P / path C)
}  // namespace

typedef __attribute__((ext_vector_type(8))) short bf16x8;
typedef __attribute__((ext_vector_type(4))) float f32x4;

#if __has_builtin(__builtin_amdgcn_exp2f)
#define EXP2(x) __builtin_amdgcn_exp2f(x)
#else
#define EXP2(x) __expf((x) * 0.6931471805599453f)
#endif

__device__ inline unsigned short f2bf(float x) {
  union { float f; unsigned u; } un; un.f = x;
  unsigned r = un.u + 0x7fffu + ((un.u >> 16) & 1u);   // RNE
  return (unsigned short)(r >> 16);
}
__device__ inline short tbf(float x) {                 // truncate (fast)
  union { float f; unsigned u; } un; un.f = x;
  return (short)(un.u >> 16);
}
__device__ inline unsigned pack2bf(float x, float y) {
  return (unsigned)f2bf(x) | ((unsigned)f2bf(y) << 16);
}
__device__ inline void gl_lds16(const short* g, short* l) {
  __builtin_amdgcn_global_load_lds(
      (const __attribute__((address_space(1))) unsigned*)g,
      (__attribute__((address_space(3))) unsigned*)l, 16, 0, 0);
}

// ---------------------------------------------------------------------------
// Merged fp32->bf16 convert: blocks [0,n0) -> a, [n0,n0+n1) -> b, rest -> c.
__global__ __launch_bounds__(256) void cvt3_kernel(
    const float* __restrict__ a, short* __restrict__ da, int n0,
    const float* __restrict__ b, short* __restrict__ db, int n1,
    const float* __restrict__ c, short* __restrict__ dc) {
  int blk = blockIdx.x;
  const float* src; short* dst;
  if (blk < n0) { src = a; dst = da; }
  else if (blk < n0 + n1) { src = b; dst = db; blk -= n0; }
  else { src = c; dst = dc; blk -= n0 + n1; }
  const int i = (blk * 256 + threadIdx.x) * 8;
  float4 u = *(const float4*)&src[i];
  float4 v = *(const float4*)&src[i + 4];
  bf16x8 o = {(short)f2bf(u.x), (short)f2bf(u.y), (short)f2bf(u.z), (short)f2bf(u.w),
              (short)f2bf(v.x), (short)f2bf(v.y), (short)f2bf(v.z), (short)f2bf(v.w)};
  *(bf16x8*)&dst[i] = o;
}

// ---------------------------------------------------------------------------
// QKV GEMM (path A): A16[4096,1024] @ W16[3072,1024]^T. 128x128 tile, BK=64,
// global_load_lds + XOR swizzle. Epilogue: Q scaled by kQScale -> [b][h][n][dh];
// K -> [b][h][n][dh]; V -> TRANSPOSED [b][h][dh][n] via per-wave LDS bounce.
__global__ __launch_bounds__(256, 2) void mm_qkv_kernel(
    const short* __restrict__ A16, const short* __restrict__ W16,
    short* __restrict__ q16, short* __restrict__ k16, short* __restrict__ vT16) {
  __shared__ short smem[2 * 128 * 64];
  short* As = smem;
  short* Bs = smem + 128 * 64;
  const int tid  = threadIdx.x;
  const int w    = tid >> 6;
  const int lane = tid & 63;
  const int quad = lane >> 4;
  const int k15  = lane & 15;
  const int m0   = blockIdx.x * 128;
  const int seg  = blockIdx.y >> 3;
  const int nt0  = (blockIdx.y & 7) << 7;
  const int wrow0 = seg * 1024 + nt0;
  const int wm = (w >> 1) * 64;
  const int wn = (w & 1) * 64;
  const int lrow   = lane >> 3;
  const int lchunk = (lane & 7) ^ lrow;

  f32x4 acc[4][4];
#pragma unroll
  for (int i = 0; i < 4; ++i)
#pragma unroll
    for (int j = 0; j < 4; ++j) acc[i][j] = (f32x4){0.f, 0.f, 0.f, 0.f};

  for (int kt = 0; kt < 1024; kt += 64) {
    __syncthreads();
#pragma unroll
    for (int p = 0; p < 4; ++p) {
      const int r0 = p * 32 + w * 8;
      gl_lds16(&A16[(long)(m0 + r0 + lrow) * 1024 + kt + lchunk * 8], &As[r0 * 64]);
      gl_lds16(&W16[(long)(wrow0 + r0 + lrow) * 1024 + kt + lchunk * 8], &Bs[r0 * 64]);
    }
    __syncthreads();
#pragma unroll
    for (int ks = 0; ks < 2; ++ks) {
      bf16x8 af[4], bf[4];
#pragma unroll
      for (int t = 0; t < 4; ++t) {
        const int Ra = wm + t * 16 + k15;
        af[t] = *(const bf16x8*)&As[Ra * 64 + (((ks << 2) + quad) ^ (Ra & 7)) * 8];
        const int Rb = wn + t * 16 + k15;
        bf[t] = *(const bf16x8*)&Bs[Rb * 64 + (((ks << 2) + quad) ^ (Rb & 7)) * 8];
      }
#pragma unroll
      for (int mt = 0; mt < 4; ++mt)
#pragma unroll
        for (int nt = 0; nt < 4; ++nt)
          acc[mt][nt] = __builtin_amdgcn_mfma_f32_16x16x32_bf16(
              af[mt], bf[nt], acc[mt][nt], 0, 0, 0);
    }
  }

  if (seg < 2) {
    short* dst = (seg == 0) ? q16 : k16;
    const float sc = (seg == 0) ? kQScale : 1.0f;
#pragma unroll
    for (int nt = 0; nt < 4; ++nt) {
      const int dl = nt0 + wn + nt * 16 + k15;
      const int h  = dl >> 6;
      const int dh = dl & 63;
#pragma unroll
      for (int mt = 0; mt < 4; ++mt) {
#pragma unroll
        for (int r = 0; r < 4; ++r) {
          const int ml = m0 + wm + mt * 16 + quad * 4 + r;
          const int b  = ml >> 11;
          const int n  = ml & 2047;
          dst[(((long)(b * kHeads + h) * kN) + n) * kHd + dh] =
              (short)f2bf(acc[mt][nt][r] * sc);
        }
      }
    }
  } else {
    __syncthreads();
    short* Tw = smem + w * 16 * kP;
#pragma unroll
    for (int nt = 0; nt < 4; ++nt) {
#pragma unroll
      for (int mt = 0; mt < 4; ++mt) {
        uint2 pk;
        pk.x = pack2bf(acc[mt][nt][0], acc[mt][nt][1]);
        pk.y = pack2bf(acc[mt][nt][2], acc[mt][nt][3]);
        *(uint2*)&Tw[k15 * kP + mt * 16 + quad * 4] = pk;
      }
#pragma unroll
      for (int i = 0; i < 2; ++i) {
        const int idx  = i * 64 + lane;
        const int trow = idx >> 3;
        const int tch  = idx & 7;
        bf16x8 row = *(const bf16x8*)&Tw[trow * kP + tch * 8];
        const int vcol = nt0 + wn + nt * 16 + trow;
        const int h  = vcol >> 6;
        const int dh = vcol & 63;
        const int m  = m0 + wm + tch * 8;
        const int b  = m >> 11;
        const int n  = m & 2047;
        *(bf16x8*)&vT16[(((long)(b * kHeads + h) * kHd) + dh) * kN + n] = row;
      }
    }
  }
}

// ---------------------------------------------------------------------------
// proj GEMM: out = ao16[4096,1024] @ PW16[1024,1024]^T + bias (fp32 out).
__global__ __launch_bounds__(256, 2) void mm_proj_kernel(
    const short* __restrict__ A16, const short* __restrict__ B16,
    const float* __restrict__ bias, float* __restrict__ out) {
  __shared__ short As[128 * 64];
  __shared__ short Bs[128 * 64];
  const int tid  = threadIdx.x;
  const int w    = tid >> 6;
  const int lane = tid & 63;
  const int quad = lane >> 4;
  const int k15  = lane & 15;
  const int m0 = blockIdx.x * 128;
  const int n0 = blockIdx.y * 128;
  const int wm = (w >> 1) * 64;
  const int wn = (w & 1) * 64;
  const int lrow   = lane >> 3;
  const int lchunk = (lane & 7) ^ lrow;

  f32x4 acc[4][4];
#pragma unroll
  for (int i = 0; i < 4; ++i)
#pragma unroll
    for (int j = 0; j < 4; ++j) acc[i][j] = (f32x4){0.f, 0.f, 0.f, 0.f};

  for (int kt = 0; kt < 1024; kt += 64) {
    __syncthreads();
#pragma unroll
    for (int p = 0; p < 4; ++p) {
      const int r0 = p * 32 + w * 8;
      gl_lds16(&A16[(long)(m0 + r0 + lrow) * 1024 + kt + lchunk * 8], &As[r0 * 64]);
      gl_lds16(&B16[(long)(n0 + r0 + lrow) * 1024 + kt + lchunk * 8], &Bs[r0 * 64]);
    }
    __syncthreads();
#pragma unroll
    for (int ks = 0; ks < 2; ++ks) {
      bf16x8 af[4], bf[4];
#pragma unroll
      for (int t = 0; t < 4; ++t) {
        const int Ra = wm + t * 16 + k15;
        af[t] = *(const bf16x8*)&As[Ra * 64 + (((ks << 2) + quad) ^ (Ra & 7)) * 8];
        const int Rb = wn + t * 16 + k15;
        bf[t] = *(const bf16x8*)&Bs[Rb * 64 + (((ks << 2) + quad) ^ (Rb & 7)) * 8];
      }
#pragma unroll
      for (int mt = 0; mt < 4; ++mt)
#pragma unroll
        for (int nt = 0; nt < 4; ++nt)
          acc[mt][nt] = __builtin_amdgcn_mfma_f32_16x16x32_bf16(
              af[mt], bf[nt], acc[mt][nt], 0, 0, 0);
    }
  }

#pragma unroll
  for (int nt = 0; nt < 4; ++nt) {
    const int d = n0 + wn + nt * 16 + k15;
    const float bb = bias[d];
#pragma unroll
    for (int mt = 0; mt < 4; ++mt) {
#pragma unroll
      for (int r = 0; r < 4; ++r) {
        const int m = m0 + wm + mt * 16 + quad * 4 + r;
        out[(long)m * 1024 + d] = acc[mt][nt][r] + bb;
      }
    }
  }
}

// ---------------------------------------------------------------------------
// Flash attention v4: wave = 32 q-rows (2x16), block = 4 waves = 128 q-rows,
// grid 512 (2 blocks/CU, 2 waves/SIMD). 128-key tiles; K [h][n][dh] and
// V^T [h][dh][n] via global_load_lds + XOR swizzle. Q pre-scaled by
// 0.125*log2(e) -> P = exp2(S), truncating bf16; row sums via ones-MFMA.
__global__ __launch_bounds__(256, 2) void attn_kernel(
    const short* __restrict__ q16, const short* __restrict__ k16,
    const short* __restrict__ vT16, short* __restrict__ ao16) {
  __shared__ short Ks[128 * 64];        // [key][dh] chunk-swizzled
  __shared__ short Vs[64 * 128];        // [dh][key] chunk-swizzled
  __shared__ short Ps[4 * 2 * 16 * kP]; // [wave][parity][16 q][64 key]

  const int tid  = threadIdx.x;         // 0..255
  const int w    = tid >> 6;            // 0..3
  const int lane = tid & 63;
  const int quad = lane >> 4;
  const int k15  = lane & 15;
  const int lrow  = lane >> 3;          // K staging
  const int lch8  = lane & 7;
  const int lrow4 = lane >> 4;          // V staging
  const int lch16 = lane & 15;
  const int bufIdx = blockIdx.z * kHeads + blockIdx.y;
  const long base  = (long)bufIdx * kN * kHd;

  // Q A-frags: 2 qt tiles x 2 k-steps
  bf16x8 qf[2][2];
#pragma unroll
  for (int qt = 0; qt < 2; ++qt) {
    const long qr = base + (long)(blockIdx.x * 128 + w * 32 + qt * 16 + k15) * kHd;
#pragma unroll
    for (int ks = 0; ks < 2; ++ks)
      qf[qt][ks] = *(const bf16x8*)&q16[qr + ks * 32 + quad * 8];
  }

  // ones B-frag: column n=0 all ones (row sums via MFMA)
  const short oneb = (short)0x3F80;
  bf16x8 onesf;
#pragma unroll
  for (int j = 0; j < 8; ++j) onesf[j] = (k15 == 0) ? oneb : (short)0;

  f32x4 accO[2][4];
#pragma unroll
  for (int qt = 0; qt < 2; ++qt)
#pragma unroll
    for (int d = 0; d < 4; ++d) accO[qt][d] = (f32x4){0.f, 0.f, 0.f, 0.f};
  f32x4 accL[2] = {{0.f,0.f,0.f,0.f},{0.f,0.f,0.f,0.f}};

  for (int kt = 0; kt < kN / 128; ++kt) {
    __syncthreads();
    {
      const short* kg = k16 + base + (long)kt * 128 * kHd;
      const short* vg = vT16 + base + kt * 128;
#pragma unroll
      for (int c = 0; c < 4; ++c) {
        const int r0 = w * 32 + c * 8;
        gl_lds16(kg + (long)(r0 + lrow) * kHd + (lch8 ^ ((r0 + lrow) & 7)) * 8,
                 &Ks[r0 * 64]);
      }
#pragma unroll
      for (int c = 0; c < 4; ++c) {
        const int r0v = w * 16 + c * 4;
        gl_lds16(vg + (long)(r0v + lrow4) * kN + (lch16 ^ ((r0v + lrow4) & 15)) * 8,
                 &Vs[r0v * 128]);
      }
    }
    __syncthreads();

#pragma unroll
    for (int h2 = 0; h2 < 2; ++h2) {
      // K B-frags (shared across qt)
      bf16x8 kb[4][2];
#pragma unroll
      for (int t = 0; t < 4; ++t) {
        const int row = h2 * 64 + t * 16 + k15;
#pragma unroll
        for (int ks = 0; ks < 2; ++ks)
          kb[t][ks] = *(const bf16x8*)&Ks[row * 64 + (((ks << 2) + quad) ^ (row & 7)) * 8];
      }
      // V B-frags (shared across qt)
      bf16x8 vb[2][4];
#pragma unroll
      for (int kc = 0; kc < 2; ++kc)
#pragma unroll
        for (int d = 0; d < 4; ++d) {
          const int vrow = d * 16 + k15;
          const int ch = (h2 * 8 + kc * 4 + quad) ^ (vrow & 15);
          vb[kc][d] = *(const bf16x8*)&Vs[vrow * 128 + ch * 8];
        }

#pragma unroll
      for (int qt = 0; qt < 2; ++qt) {
        f32x4 sc[4];
#pragma unroll
        for (int t = 0; t < 4; ++t) {
          f32x4 z = {0.f, 0.f, 0.f, 0.f};
          z = __builtin_amdgcn_mfma_f32_16x16x32_bf16(qf[qt][0], kb[t][0], z, 0, 0, 0);
          z = __builtin_amdgcn_mfma_f32_16x16x32_bf16(qf[qt][1], kb[t][1], z, 0, 0, 0);
          sc[t] = z;
        }
        short* pw = Ps + (w * 2 + qt) * 16 * kP;
#pragma unroll
        for (int t = 0; t < 4; ++t)
#pragma unroll
          for (int r = 0; r < 4; ++r)
            pw[(quad * 4 + r) * kP + t * 16 + k15] = tbf(EXP2(sc[t][r]));
#pragma unroll
        for (int kc = 0; kc < 2; ++kc) {
          bf16x8 pf = *(const bf16x8*)&pw[k15 * kP + kc * 32 + quad * 8];
#pragma unroll
          for (int d = 0; d < 4; ++d)
            accO[qt][d] = __builtin_amdgcn_mfma_f32_16x16x32_bf16(
                pf, vb[kc][d], accO[qt][d], 0, 0, 0);
          accL[qt] = __builtin_amdgcn_mfma_f32_16x16x32_bf16(
              pf, onesf, accL[qt], 0, 0, 0);
        }
      }
    }
  }

#pragma unroll
  for (int qt = 0; qt < 2; ++qt) {
#pragma unroll
    for (int r = 0; r < 4; ++r) {
      const float s  = __shfl(accL[qt][r], (lane & 48));  // col-0 lane of quad
      const float in = 1.f / s;
      const int gq = blockIdx.x * 128 + w * 32 + qt * 16 + quad * 4 + r;
      short* drow = ao16 + ((long)(blockIdx.z * kN + gq)) * kDim + blockIdx.y * kHd;
#pragma unroll
      for (int d = 0; d < 4; ++d)
        drow[d * 16 + k15] = (short)f2bf(accO[qt][d][r] * in);
    }
  }
}

// ---------------------------------------------------------------------------
// Path C fallback (proven r3-style, 20 MiB): fp32-input VGPR-staged kernels.
__global__ __launch_bounds__(256, 2) void r3_qkv_kernel(
    const float* __restrict__ X, const float* __restrict__ W,
    short* __restrict__ q16, short* __restrict__ k16, short* __restrict__ v16) {
  __shared__ short As[128 * kP];
  __shared__ short Ws[128 * kP];
  const int tid  = threadIdx.x;
  const int w    = tid >> 6;
  const int lane = tid & 63;
  const int quad = lane >> 4;
  const int k15  = lane & 15;
  const int m0 = blockIdx.x * 128;
  const int n0 = blockIdx.y * 128;
  const int wm = (w >> 1) * 64;
  const int wn = (w & 1) * 64;

  f32x4 acc[4][4];
#pragma unroll
  for (int i = 0; i < 4; ++i)
#pragma unroll
    for (int j = 0; j < 4; ++j) acc[i][j] = (f32x4){0.f, 0.f, 0.f, 0.f};

  for (int kt = 0; kt < kDim; kt += 64) {
    __syncthreads();
#pragma unroll
    for (int p = 0; p < 8; ++p) {
      const int idx = p * 256 + tid;
      const int row = idx >> 4;
      const int c4  = (idx & 15) << 2;
      float4 av = *(const float4*)&X[(long)(m0 + row) * kDim + kt + c4];
      uint2 ap = {pack2bf(av.x, av.y), pack2bf(av.z, av.w)};
      *(uint2*)&As[row * kP + c4] = ap;
      float4 wv = *(const float4*)&W[(long)(n0 + row) * kDim + kt + c4];
      uint2 wp = {pack2bf(wv.x, wv.y), pack2bf(wv.z, wv.w)};
      *(uint2*)&Ws[row * kP + c4] = wp;
    }
    __syncthreads();
#pragma unroll
    for (int ks = 0; ks < 2; ++ks) {
      bf16x8 af[4], bf[4];
#pragma unroll
      for (int t = 0; t < 4; ++t) {
        af[t] = *(const bf16x8*)&As[(wm + t * 16 + k15) * kP + ks * 32 + quad * 8];
        bf[t] = *(const bf16x8*)&Ws[(wn + t * 16 + k15) * kP + ks * 32 + quad * 8];
      }
#pragma unroll
      for (int mt = 0; mt < 4; ++mt)
#pragma unroll
        for (int nt = 0; nt < 4; ++nt)
          acc[mt][nt] = __builtin_amdgcn_mfma_f32_16x16x32_bf16(
              af[mt], bf[nt], acc[mt][nt], 0, 0, 0);
    }
  }

  const int t_sel = n0 >> 10;
  short* dst = (t_sel == 0) ? q16 : (t_sel == 1) ? k16 : v16;
  const float scl = (t_sel == 0) ? kScale : 1.0f;
#pragma unroll
  for (int nt = 0; nt < 4; ++nt) {
    const int d  = n0 + wn + nt * 16 + k15;
    const int h  = (d >> 6) & 15;
    const int dh = d & 63;
#pragma unroll
    for (int mt = 0; mt < 4; ++mt) {
#pragma unroll
      for (int r = 0; r < 4; ++r) {
        const int m = m0 + wm + mt * 16 + quad * 4 + r;
        dst[((long)h * kN + m) * kHd + dh] = (short)f2bf(acc[mt][nt][r] * scl);
      }
    }
  }
}

__global__ __launch_bounds__(256, 4) void attn_v1_kernel(
    const short* __restrict__ q16, const short* __restrict__ k16,
    const short* __restrict__ v16, short* __restrict__ ao16, int bpar) {
  __shared__ short Ks[64 * kP];
  __shared__ short Vs[64 * kP];
  __shared__ short Ps[4 * 16 * kP];
  const int tid  = threadIdx.x;
  const int w    = tid >> 6;
  const int lane = tid & 63;
  const int quad = lane >> 4;
  const int k15  = lane & 15;
  const long base = (long)blockIdx.y * kN * kHd;
  const int qrow = blockIdx.x * 64 + w * 16 + k15;
  const short* qp = q16 + base + (long)qrow * kHd + quad * 8;
  bf16x8 qf0 = *(const bf16x8*)(qp);
  bf16x8 qf1 = *(const bf16x8*)(qp + 32);

  f32x4 accO[4] = {{0.f,0.f,0.f,0.f},{0.f,0.f,0.f,0.f},
                   {0.f,0.f,0.f,0.f},{0.f,0.f,0.f,0.f}};
  float lsum[4] = {0.f, 0.f, 0.f, 0.f};

  for (int kt = 0; kt < kN / 64; ++kt) {
    __syncthreads();
    {
      const short* kg = k16 + base + (long)kt * 64 * kHd;
      const short* vg = v16 + base + (long)kt * 64 * kHd;
#pragma unroll
      for (int p = 0; p < 2; ++p) {
        const int idx = p * 256 + tid;
        const int key = idx >> 3;
        const int c8  = (idx & 7) << 3;
        *(bf16x8*)&Ks[key * kP + c8] = *(const bf16x8*)&kg[key * kHd + c8];
        bf16x8 vv = *(const bf16x8*)&vg[key * kHd + c8];
#pragma unroll
        for (int j = 0; j < 8; ++j) Vs[(c8 + j) * kP + key] = vv[j];
      }
    }
    __syncthreads();

    f32x4 sc[4];
#pragma unroll
    for (int t = 0; t < 4; ++t) {
      bf16x8 kb0 = *(const bf16x8*)&Ks[(t * 16 + k15) * kP + quad * 8];
      bf16x8 kb1 = *(const bf16x8*)&Ks[(t * 16 + k15) * kP + 32 + quad * 8];
      f32x4 z = {0.f, 0.f, 0.f, 0.f};
      z = __builtin_amdgcn_mfma_f32_16x16x32_bf16(qf0, kb0, z, 0, 0, 0);
      z = __builtin_amdgcn_mfma_f32_16x16x32_bf16(qf1, kb1, z, 0, 0, 0);
      sc[t] = z;
    }
    short* pw = &Ps[w * (16 * kP)];
#pragma unroll
    for (int t = 0; t < 4; ++t) {
#pragma unroll
      for (int r = 0; r < 4; ++r) {
        const float p = __expf(sc[t][r]);
        lsum[r] += p;
        pw[(quad * 4 + r) * kP + t * 16 + k15] = (short)f2bf(p);
      }
    }
    bf16x8 pf0 = *(const bf16x8*)&pw[k15 * kP + quad * 8];
    bf16x8 pf1 = *(const bf16x8*)&pw[k15 * kP + 32 + quad * 8];
#pragma unroll
    for (int t = 0; t < 4; ++t) {
      bf16x8 vb0 = *(const bf16x8*)&Vs[(t * 16 + k15) * kP + quad * 8];
      bf16x8 vb1 = *(const bf16x8*)&Vs[(t * 16 + k15) * kP + 32 + quad * 8];
      accO[t] = __builtin_amdgcn_mfma_f32_16x16x32_bf16(pf0, vb0, accO[t], 0, 0, 0);
      accO[t] = __builtin_amdgcn_mfma_f32_16x16x32_bf16(pf1, vb1, accO[t], 0, 0, 0);
    }
  }

#pragma unroll
  for (int r = 0; r < 4; ++r) {
    float s = lsum[r];
    s += __shfl_xor(s, 1);
    s += __shfl_xor(s, 2);
    s += __shfl_xor(s, 4);
    s += __shfl_xor(s, 8);
    lsum[r] = 1.f / s;
  }
#pragma unroll
  for (int r = 0; r < 4; ++r) {
    const int gq = blockIdx.x * 64 + w * 16 + quad * 4 + r;
    short* drow = ao16 + ((long)(bpar * kN + gq)) * kDim + blockIdx.y * kHd;
#pragma unroll
    for (int t = 0; t < 4; ++t)
      drow[t * 16 + k15] = (short)f2bf(accO[t][r] * lsum[r]);
  }
}

__global__ __launch_bounds__(256, 2) void r3_proj_kernel(
    const short* __restrict__ A16, const float* __restrict__ W,
    const float* __restrict__ bias, float* __restrict__ out) {
  __shared__ short As[128 * kP];
  __shared__ short Ws[128 * kP];
  const int tid  = threadIdx.x;
  const int w    = tid >> 6;
  const int lane = tid & 63;
  const int quad = lane >> 4;
  const int k15  = lane & 15;
  const int m0 = blockIdx.x * 128;
  const int n0 = blockIdx.y * 128;
  const int wm = (w >> 1) * 64;
  const int wn = (w & 1) * 64;

  f32x4 acc[4][4];
#pragma unroll
  for (int i = 0; i < 4; ++i)
#pragma unroll
    for (int j = 0; j < 4; ++j) acc[i][j] = (f32x4){0.f, 0.f, 0.f, 0.f};

  for (int kt = 0; kt < kDim; kt += 64) {
    __syncthreads();
#pragma unroll
    for (int p = 0; p < 4; ++p) {
      const int idx = p * 256 + tid;
      const int row = idx >> 3;
      const int c8  = (idx & 7) << 3;
      *(bf16x8*)&As[row * kP + c8] =
          *(const bf16x8*)&A16[(long)(m0 + row) * kDim + kt + c8];
    }
#pragma unroll
    for (int p = 0; p < 8; ++p) {
      const int idx = p * 256 + tid;
      const int row = idx >> 4;
      const int c4  = (idx & 15) << 2;
      float4 wv = *(const float4*)&W[(long)(n0 + row) * kDim + kt + c4];
      uint2 wp = {pack2bf(wv.x, wv.y), pack2bf(wv.z, wv.w)};
      *(uint2*)&Ws[row * kP + c4] = wp;
    }
    __syncthreads();
#pragma unroll
    for (int ks = 0; ks < 2; ++ks) {
      bf16x8 af[4], bf[4];
#pragma unroll
      for (int t = 0; t < 4; ++t) {
        af[t] = *(const bf16x8*)&As[(wm + t * 16 + k15) * kP + ks * 32 + quad * 8];
        bf[t] = *(const bf16x8*)&Ws[(wn + t * 16 + k15) * kP + ks * 32 + quad * 8];
      }
#pragma unroll
      for (int mt = 0; mt < 4; ++mt)
#pragma unroll
        for (int nt = 0; nt < 4; ++nt)
          acc[mt][nt] = __builtin_amdgcn_mfma_f32_16x16x32_bf16(
              af[mt], bf[nt], acc[mt][nt], 0, 0, 0);
    }
  }

#pragma unroll
  for (int nt = 0; nt < 4; ++nt) {
    const int d = n0 + wn + nt * 16 + k15;
    const float bb = bias[d];
#pragma unroll
    for (int mt = 0; mt < 4; ++mt) {
#pragma unroll
      for (int r = 0; r < 4; ++r) {
        const int m = m0 + wm + mt * 16 + quad * 4 + r;
        out[(long)m * kDim + d] = acc[mt][nt][r] + bb;
      }
    }
  }
}

// ---------------------------------------------------------------------------
extern "C" void kernel_launch(void* const* d_in, const int* in_sizes, int n_in,
                              void* d_out, int out_size, void* d_ws, size_t ws_size,
                              hipStream_t stream) {
  const float* x      = (const float*)d_in[0];
  const float* qkv_w  = (const float*)d_in[1];
  const float* proj_w = (const float*)d_in[2];
  const float* proj_b = (const float*)d_in[3];
  float* out = (float*)d_out;

  short* ws = (short*)d_ws;
  const size_t MiS = 1048576;

  if (ws_size >= 41943040ull) {
    // Path A (40 MiB): X16 aliased with ao.
    short* X16  = ws;              // [4096,1024]
    short* W16  = ws + 4 * MiS;    // [3072,1024]
    short* PW16 = ws + 7 * MiS;    // [1024,1024]
    short* q16  = ws + 8 * MiS;    // [2][16][2048][64]
    short* k16  = ws + 12 * MiS;   // [2][16][2048][64]
    short* vT16 = ws + 16 * MiS;   // [2][16][64][2048]
    short* ao16 = X16;

    cvt3_kernel<<<4096, 256, 0, stream>>>(x, X16, 2048, qkv_w, W16, 1536,
                                          proj_w, PW16);
    mm_qkv_kernel<<<dim3(32, 24), 256, 0, stream>>>(X16, W16, q16, k16, vT16);
    attn_kernel<<<dim3(16, 16, 2), 256, 0, stream>>>(q16, k16, vT16, ao16);
    mm_proj_kernel<<<dim3(32, 8), 256, 0, stream>>>(ao16, PW16, proj_b, out);
    return;
  }

  // Path C fallback (20 MiB, proven structure).
  {
    short* q16  = ws;
    short* k16  = ws + 2 * MiS;
    short* v16  = ws + 4 * MiS;
    short* ao16 = ws + 6 * MiS;
    for (int b = 0; b < kB; ++b) {
      r3_qkv_kernel<<<dim3(16, 24), 256, 0, stream>>>(
          x + (size_t)b * kN * kDim, qkv_w, q16, k16, v16);
      attn_v1_kernel<<<dim3(32, 16), 256, 0, stream>>>(q16, k16, v16, ao16, b);
    }
    r3_proj_kernel<<<dim3(32, 8), 256, 0, stream>>>(ao16, proj_w, proj_b, out);
  }
}